// Round 6
// baseline (327.994 us; speedup 1.0000x reference)
//
#include <hip/hip_runtime.h>
#include <math.h>

typedef __attribute__((ext_vector_type(8)))  short bf16x8;   // 8 bf16 = 4 VGPR
typedef __attribute__((ext_vector_type(16))) float f32x16;   // 32x32 MFMA acc
typedef __attribute__((ext_vector_type(4)))  float f32x4;
typedef __attribute__((ext_vector_type(4)))  unsigned uint4v;

#define MFMA32(a, b, c) __builtin_amdgcn_mfma_f32_32x32x16_bf16((a), (b), (c), 0, 0, 0)

namespace {
constexpr int HWF   = 256;
constexpr int MEMD  = 1024;
constexpr int NROWS = 65536;
constexpr int TM    = 128;          // token rows per block: 4 waves x 32 rows
constexpr int NT    = MEMD / 32;    // 32 j-tiles of 32
constexpr int THREADS = 256;        // 4 waves; 2 blocks/CU (reg-capped)
constexpr float C1v  = 0.01f;
constexpr float C2v  = 0.03f;
constexpr float EPSv = 1e-8f;
constexpr float RK   = 1.0f / 255.0f;

// LDS map (bytes): K dbuf | stats (one-shot SoA) | l-redistribute
// (V is NOT staged this round: PV reads the global transposed V blob.)
constexpr int KB0 = 0;              // 16 KB K tile (32 rows x 512B, xor-swizzled)
constexpr int KB1 = 16384;
constexpr int STATS = 32768;        // 12 KB: sa[1024] | sb[1024] | sc[1024]
constexpr int LRED  = STATS + 12288;  // 4 waves x 32 x f32 = 512 B
constexpr int SMEM_SZ = LRED + 512;   // 45568 B
}

__device__ __forceinline__ short f2bf(float f) {            // RNE float->bf16
    union { float f; unsigned u; } v; v.f = f;
    unsigned r = v.u + 0x7fffu + ((v.u >> 16) & 1u);
    return (short)(r >> 16);
}

// packed f32 pair -> 2 bf16 in one u32 (src0 -> [15:0], src1 -> [31:16]), RNE
__device__ __forceinline__ unsigned cvtpk(float a, float b) {
    unsigned r;
    asm("v_cvt_pk_bf16_f32 %0, %1, %2" : "=v"(r) : "v"(a), "v"(b));
    return r;
}

// v_permlane32_swap_b32: a.lanes[32..63] <-> b.lanes[0..31].
__device__ __forceinline__ void plswap(unsigned &a, unsigned &b) {
#if defined(__has_builtin) && __has_builtin(__builtin_amdgcn_permlane32_swap)
    auto r = __builtin_amdgcn_permlane32_swap((int)a, (int)b, false, false);
    a = (unsigned)r[0]; b = (unsigned)r[1];
#else
    const bool h = (threadIdx.x & 32) != 0;
    const unsigned ax = (unsigned)__shfl_xor((int)a, 32);
    const unsigned bx = (unsigned)__shfl_xor((int)b, 32);
    const unsigned na = h ? bx : a;
    const unsigned nb = h ? b : ax;
    a = na; b = nb;
#endif
}

// async global->LDS DMA: 16 KB tile, wave w (of 4) copies [w*4096, w*4096+4096)
__device__ __forceinline__ void dma_tile16(const short* gbase, char* smem, int ldsbase,
                                           int wave, int lane) {
    const char* g = (const char*)gbase + wave * 4096 + lane * 16;
    char* l = smem + ldsbase + wave * 4096;
    #pragma unroll
    for (int i = 0; i < 4; ++i) {
        __builtin_amdgcn_global_load_lds(
            (const __attribute__((address_space(1))) unsigned int*)(g + i * 1024),
            (__attribute__((address_space(3))) unsigned int*)(l + i * 1024), 16, 0, 0);
    }
}

// ---------------------------------------------------------------------------
// cast_w: Wq/Wk/Wv -> bf16 (blocks 0-31: Wq, 32-63: Wk, 64-95: Wv)
// ---------------------------------------------------------------------------
__global__ __launch_bounds__(256) void cast_w(
    const float* __restrict__ Wq, const float* __restrict__ Wk,
    const float* __restrict__ Wv, short* __restrict__ wq_bf,
    short* __restrict__ wk_bf, short* __restrict__ wv_bf)
{
    const int b = blockIdx.x, t = threadIdx.x;
    const float* src = (b < 32) ? Wq : (b < 64) ? Wk : Wv;
    short* dst = (b < 32) ? wq_bf : (b < 64) ? wk_bf : wv_bf;
    const int i = (b & 31) * 2048 + t * 8;
    const float4 a = *reinterpret_cast<const float4*>(src + i);
    const float4 c = *reinterpret_cast<const float4*>(src + i + 4);
    uint4v u;
    u[0] = cvtpk(a.x, a.y); u[1] = cvtpk(a.z, a.w);
    u[2] = cvtpk(c.x, c.y); u[3] = cvtpk(c.z, c.w);
    *reinterpret_cast<uint4v*>(dst + i) = u;
}

// ---------------------------------------------------------------------------
// prep_mfma: k = m@Wk^T and v = m@Wv^T via MFMA (swapped-operand frags:
// A = W rows, B = mem rows -> D col = j). Blocks 0-7: K (swizzled DMA-able
// blob + 3-array stats, round-4 verified). Blocks 8-15: V (transposed
// [c][1024] blob for direct global PV reads).
// MFMA 32x32x16: A[m=lane&31][k=8*hi+e], B[k=8*hi+e][n=lane&31],
//                D col=lane&31, row=(i&3)+8*(i>>2)+4*hi (+32*nt).
// ---------------------------------------------------------------------------
__global__ __launch_bounds__(256) void prep_mfma(
    const float* __restrict__ mem, const short* __restrict__ wk_bf,
    const short* __restrict__ wv_bf, short* __restrict__ kblob,
    short* __restrict__ vblob_t, float* __restrict__ sblob)
{
    const int t = threadIdx.x, wave = t >> 6, lane = t & 63;
    const int lo = lane & 31, hi = lane >> 5;
    const bool isV = blockIdx.x >= 8;
    const int jb = (blockIdx.x & 7) * 128 + wave * 32;  // wave's 32 j-rows
    const int j  = jb + lo;                              // this lane's j (D col)

    // B-frags from mem rows (fp32 -> bf16 in-register)
    bf16x8 mB[16];
    {
        const float* mr = mem + (size_t)j * HWF;
        #pragma unroll
        for (int s = 0; s < 16; ++s) {
            const float4 a = *reinterpret_cast<const float4*>(mr + 16 * s + 8 * hi);
            const float4 b = *reinterpret_cast<const float4*>(mr + 16 * s + 8 * hi + 4);
            uint4v u;
            u[0] = cvtpk(a.x, a.y); u[1] = cvtpk(a.z, a.w);
            u[2] = cvtpk(b.x, b.y); u[3] = cvtpk(b.z, b.w);
            mB[s] = __builtin_bit_cast(bf16x8, u);
        }
    }

    const short* W = isV ? wv_bf : wk_bf;
    f32x16 D[8];
    #pragma unroll
    for (int nt = 0; nt < 8; ++nt) D[nt] = (f32x16)(0.f);
    #pragma unroll
    for (int nt = 0; nt < 8; ++nt) {
        #pragma unroll
        for (int s = 0; s < 16; ++s) {
            const bf16x8 wa = *reinterpret_cast<const bf16x8*>(
                W + (size_t)(32 * nt + lo) * HWF + 16 * s + 8 * hi);
            D[nt] = MFMA32(wa, mB[s], D[nt]);
        }
    }

    const int jt = jb >> 5, ro = lo;        // jb is a multiple of 32
    if (!isV) {
        // per-j stats (in-lane over 128 regs + partner half)
        float s = 0.f, ss = 0.f;
        #pragma unroll
        for (int nt = 0; nt < 8; ++nt)
            #pragma unroll
            for (int i = 0; i < 16; ++i) {
                const float v = D[nt][i];
                s += v; ss = __builtin_fmaf(v, v, ss);
            }
        s += __shfl_xor(s, 32);
        ss += __shfl_xor(ss, 32);
        const float km = s * (1.f / HWF);
        const float kv = (ss - s * s * (1.f / HWF)) * (1.f / (HWF - 1));
        // K blob: [jt][ro][512B: chunk(f>>3)^(ro&7)][8 bf16]; f = 32nt+8a+4hi+e
        #pragma unroll
        for (int nt = 0; nt < 8; ++nt) {
            #pragma unroll
            for (int a = 0; a < 4; ++a) {
                short4 q4;
                q4.x = f2bf(D[nt][4 * a + 0] - km);
                q4.y = f2bf(D[nt][4 * a + 1] - km);
                q4.z = f2bf(D[nt][4 * a + 2] - km);
                q4.w = f2bf(D[nt][4 * a + 3] - km);
                *reinterpret_cast<short4*>(
                    kblob + jt * 8192 + ro * 256 +
                    (((4 * nt + a) ^ (ro & 7)) * 8) + 4 * hi) = q4;
            }
        }
        if (hi == 0) {
            sblob[j]        = 2.f * km;
            sblob[1024 + j] = km * km + C1v;
            sblob[2048 + j] = kv + C2v;
        }
    } else {
        // V blob (transposed): [f][j], j contiguous
        #pragma unroll
        for (int nt = 0; nt < 8; ++nt) {
            #pragma unroll
            for (int i = 0; i < 16; ++i) {
                const int f = 32 * nt + (i & 3) + 8 * (i >> 2) + 4 * hi;
                vblob_t[(size_t)f * MEMD + j] = f2bf(D[nt][i]);
            }
        }
    }
}

// ---------------------------------------------------------------------------
// attn: round-4 kernel with exactly ONE change (bisect): V is read directly
// from the global transposed blob [c][1024] instead of LDS staging. K and
// stats keep the verified round-4 DMA/LDS paths. Barrier per tile drains
// the K DMA only.
//   QK  A-frag: LDS K tile, xor-swizzled (round-4)
//   PV  B-frag: vblob_t[c=32ct+lo][j=32jt+16h+8hi+e] -> contiguous 16B/lane
// MFMA 32x32x16 layouts (HW-verified m74/m101):
//   A[m=lane&31][k=8*hi+e], B[k=8*hi+e][n=lane&31],
//   D col=lane&31, row=(reg&3)+8*(reg>>2)+4*hi.
// ---------------------------------------------------------------------------
__global__ __launch_bounds__(THREADS, 2) void attn(
    const float* __restrict__ x, const short* __restrict__ wq_bf,
    const short* __restrict__ kblob, const short* __restrict__ vblob_t,
    const float* __restrict__ sblob, float* __restrict__ out)
{
    __shared__ __align__(16) char smem[SMEM_SZ];
    const int t = threadIdx.x, wave = t >> 6, lane = t & 63;
    const int lo = lane & 31, hi = lane >> 5;
    const int rg = wave;                    // 4 row-groups of 32 tokens
    const int n0 = blockIdx.x * TM;
    const int tok = n0 + 32 * rg + lo;      // this lane's token row

    // ---- DMA K tile 0 + one-shot stats immediately (overlaps prologue) ----
    dma_tile16(kblob, smem, KB0, wave, lane);
    #pragma unroll
    for (int r = 0; r < 3; ++r) {           // 12 KB stats: 3 rounds x 4 waves x 1 KB
        __builtin_amdgcn_global_load_lds(
            (const __attribute__((address_space(1))) unsigned int*)
                ((const char*)sblob + r * 4096 + wave * 1024 + lane * 16),
            (__attribute__((address_space(3))) unsigned int*)
                (smem + STATS + r * 4096 + wave * 1024 + lane * 16), 16, 0, 0);
    }

    // ---- x B-frags: lane = token (n index), regs = feature ----
    bf16x8 xB[16];
    {
        const float* xr = x + (size_t)tok * HWF;
        #pragma unroll
        for (int s = 0; s < 16; ++s) {
            const float4 a = *reinterpret_cast<const float4*>(xr + 16 * s + 8 * hi);
            const float4 b = *reinterpret_cast<const float4*>(xr + 16 * s + 8 * hi + 4);
            uint4v u;
            u[0] = cvtpk(a.x, a.y); u[1] = cvtpk(a.z, a.w);
            u[2] = cvtpk(b.x, b.y); u[3] = cvtpk(b.z, b.w);
            xB[s] = __builtin_bit_cast(bf16x8, u);
        }
    }

    // ---- q = Wq @ x^T (swapped): D col = token, row = out-feature ----
    f32x16 qD[8];
    #pragma unroll
    for (int nt = 0; nt < 8; ++nt) qD[nt] = (f32x16)(0.f);
    #pragma unroll
    for (int nt = 0; nt < 8; ++nt) {
        #pragma unroll
        for (int s = 0; s < 16; ++s) {
            const bf16x8 wa = *reinterpret_cast<const bf16x8*>(
                wq_bf + (size_t)(32 * nt + lo) * HWF + 16 * s + 8 * hi);
            qD[nt] = MFMA32(wa, xB[s], qD[nt]);
        }
    }

    // ---- per-token stats fully in-lane (own half + partner half) ----
    float qs = 0.f, qss = 0.f;
    #pragma unroll
    for (int nt = 0; nt < 8; ++nt)
        #pragma unroll
        for (int i = 0; i < 16; ++i) {
            const float v = qD[nt][i];
            qs += v; qss = __builtin_fmaf(v, v, qss);
        }
    qs += __shfl_xor(qs, 32);
    qss += __shfl_xor(qss, 32);
    const float qm  = qs * (1.f / HWF);
    const float qv  = (qss - qs * qs * (1.f / HWF)) * (1.f / (HWF - 1));
    const float qm2 = qm * qm;

    // ---- qA frags in-register: cvt_pk pairs + permlane32_swap ----
    bf16x8 qA[16];
    #pragma unroll
    for (int nt = 0; nt < 8; ++nt) {
        unsigned w[8];
        #pragma unroll
        for (int p = 0; p < 8; ++p) w[p] = cvtpk(qD[nt][2 * p], qD[nt][2 * p + 1]);
        #pragma unroll
        for (int h = 0; h < 2; ++h) {
            unsigned a0 = w[4 * h + 0], b0 = w[4 * h + 2];
            unsigned a1 = w[4 * h + 1], b1 = w[4 * h + 3];
            plswap(a0, b0); plswap(a1, b1);
            uint4v u; u[0] = a0; u[1] = a1; u[2] = b0; u[3] = b1;
            qA[2 * nt + h] = __builtin_bit_cast(bf16x8, u);
        }
    }

    // ---- main loop over 32 j-tiles ----
    f32x16 O4[8];
    #pragma unroll
    for (int ct = 0; ct < 8; ++ct) O4[ct] = (f32x16)(0.f);
    float l = 0.f;
    const int rx = (lo & 7);                // K xor-swizzle key
    const short* vt_base = vblob_t + (size_t)lo * MEMD + 8 * hi;

    for (int jt = 0; jt < NT; ++jt) {
        const int cur = jt & 1;
        const int kb = cur ? KB1 : KB0;
        const int kbn = cur ? KB0 : KB1;
        __syncthreads();                    // drains K DMA(jt); prev tile reads done
        if (jt + 1 < NT) {                  // prefetch stays in flight across compute
            dma_tile16(kblob + (size_t)(jt + 1) * 8192, smem, kbn, wave, lane);
        }

        // ---- S = K @ q^T : lane = token, regs = j-offset (32 j) ----
        f32x16 sacc = (f32x16)(0.f);
        __builtin_amdgcn_s_setprio(1);
        #pragma unroll
        for (int s = 0; s < 16; ++s) {
            const bf16x8 kfr = *reinterpret_cast<const bf16x8*>(
                smem + kb + lo * 512 + (((2 * s + hi) ^ rx) * 16));
            sacc = MFMA32(kfr, qA[s], sacc);
        }
        __builtin_amdgcn_s_setprio(0);

        // ---- ssim -> p -> packed bf16 pairs (stats via row-vector reads) ----
        unsigned pw[8];
        #pragma unroll
        for (int g = 0; g < 4; ++g) {
            const int soff = (32 * jt + 8 * g + 4 * hi) * 4;
            const f32x4 a4 = *reinterpret_cast<const f32x4*>(smem + STATS + soff);
            const f32x4 b4 = *reinterpret_cast<const f32x4*>(smem + STATS + 4096 + soff);
            const f32x4 c4 = *reinterpret_cast<const f32x4*>(smem + STATS + 8192 + soff);
            float pr[4];
            #pragma unroll
            for (int q = 0; q < 4; ++q) {
                const int i = 4 * g + q;
                const float cov2 = __builtin_fmaf(sacc[i], 2.f * RK, C2v);
                const float num  = __builtin_fmaf(a4[q], qm, C1v) * cov2;
                const float den  = __builtin_fmaf(qm2 + b4[q], qv + c4[q], EPSv);
                pr[q] = __expf(__fdividef(num, den));
                l += pr[q];
            }
            pw[2 * g]     = cvtpk(pr[0], pr[1]);
            pw[2 * g + 1] = cvtpk(pr[2], pr[3]);
        }

        // ---- O += P @ V : A-frags via permlane32_swap, B direct from global ----
        #pragma unroll
        for (int h = 0; h < 2; ++h) {
            unsigned a0 = pw[4 * h + 0], b0 = pw[4 * h + 2];
            unsigned a1 = pw[4 * h + 1], b1 = pw[4 * h + 3];
            plswap(a0, b0); plswap(a1, b1);
            uint4v u; u[0] = a0; u[1] = a1; u[2] = b0; u[3] = b1;
            const bf16x8 pa = __builtin_bit_cast(bf16x8, u);
            __builtin_amdgcn_s_setprio(1);
            #pragma unroll
            for (int ct = 0; ct < 8; ++ct) {
                const bf16x8 vfr = *reinterpret_cast<const bf16x8*>(
                    vt_base + (size_t)ct * (32 * MEMD) + 32 * jt + 16 * h);
                O4[ct] = MFMA32(pa, vfr, O4[ct]);
            }
            __builtin_amdgcn_s_setprio(0);
        }
    }

    // ---- l: lane-sum -> per-row via tiny wave-local LDS redistribute ----
    const float lf = l + __shfl_xor(l, 32);
    if (hi == 0)
        *reinterpret_cast<float*>(smem + LRED + (wave * 32 + lo) * 4) = lf;
    // same-wave DS ops complete in order; reads below see the writes
    float rl[16];
    #pragma unroll
    for (int g = 0; g < 4; ++g) {
        const f32x4 lv = *reinterpret_cast<const f32x4*>(
            smem + LRED + wave * 128 + (8 * g + 4 * hi) * 4);
        rl[4 * g + 0] = 1.f / lv[0];
        rl[4 * g + 1] = 1.f / lv[1];
        rl[4 * g + 2] = 1.f / lv[2];
        rl[4 * g + 3] = 1.f / lv[3];
    }

    #pragma unroll
    for (int ct = 0; ct < 8; ++ct) {
        #pragma unroll
        for (int i = 0; i < 16; ++i) {
            const int row = 32 * rg + (i & 3) + 8 * (i >> 2) + 4 * hi;
            out[(size_t)(n0 + row) * HWF + 32 * ct + lo] = O4[ct][i] * rl[i];
        }
    }
}

extern "C" void kernel_launch(void* const* d_in, const int* in_sizes, int n_in,
                              void* d_out, int out_size, void* d_ws, size_t ws_size,
                              hipStream_t stream) {
    (void)in_sizes; (void)n_in; (void)out_size; (void)ws_size;
    const float* x   = (const float*)d_in[0];
    const float* mem = (const float*)d_in[1];
    const float* Wq  = (const float*)d_in[2];
    const float* Wk  = (const float*)d_in[3];
    const float* Wv  = (const float*)d_in[4];
    float* out = (float*)d_out;

    // workspace (~1.2 MB): wq_bf | kblob (swizzled) | vblob_t | sblob (SoA)
    short* wq_bf   = (short*)d_ws;                        // 65536
    short* kblob   = wq_bf + 65536;                       // 262144 (32 tiles x 8192)
    short* vblob_t = kblob + (size_t)MEMD * HWF;          // 262144
    float* sblob   = (float*)(vblob_t + (size_t)MEMD * HWF);  // 3072 floats

    // Wk/Wv bf16 scratch lives in the head of `out` (64 MB): written by
    // cast_w, read by prep_mfma, fully overwritten later by attn.
    short* wk_bf = (short*)out;                           // 65536 shorts
    short* wv_bf = wk_bf + 65536;                         // 65536 shorts

    cast_w<<<96, 256, 0, stream>>>(Wq, Wk, Wv, wq_bf, wk_bf, wv_bf);
    prep_mfma<<<16, 256, 0, stream>>>(mem, wk_bf, wv_bf, kblob, vblob_t, sblob);
    attn<<<NROWS / TM, THREADS, 0, stream>>>(x, wq_bf, kblob, vblob_t, sblob, out);
}

// Round 7
// 313.389 us; speedup vs baseline: 1.0466x; 1.0466x over previous
//
#include <hip/hip_runtime.h>
#include <math.h>

typedef __attribute__((ext_vector_type(8)))  short bf16x8;   // 8 bf16 = 4 VGPR
typedef __attribute__((ext_vector_type(16))) float f32x16;   // 32x32 MFMA acc
typedef __attribute__((ext_vector_type(4)))  float f32x4;
typedef __attribute__((ext_vector_type(4)))  unsigned uint4v;

#define MFMA32(a, b, c) __builtin_amdgcn_mfma_f32_32x32x16_bf16((a), (b), (c), 0, 0, 0)

namespace {
constexpr int HWF   = 256;
constexpr int MEMD  = 1024;
constexpr int NROWS = 65536;
constexpr int TM    = 128;          // token rows per block: 4 waves x 32 rows
constexpr int NT    = MEMD / 32;    // 32 j-tiles of 32
constexpr int THREADS = 256;        // 4 waves; 2 blocks/CU (reg-capped)
constexpr float C1v  = 0.01f;
constexpr float C2v  = 0.03f;
constexpr float EPSv = 1e-8f;
constexpr float RK   = 1.0f / 255.0f;

// LDS map (bytes): stats (one-shot SoA) | l-redistribute. No K/V staging.
constexpr int STATS = 0;            // 12 KB: sa[1024] | sb[1024] | sc[1024]
constexpr int LRED  = 12288;        // 4 waves x 32 x f32 = 512 B
constexpr int SMEM_SZ = LRED + 512; // 12800 B
}

__device__ __forceinline__ short f2bf(float f) {            // RNE float->bf16
    union { float f; unsigned u; } v; v.f = f;
    unsigned r = v.u + 0x7fffu + ((v.u >> 16) & 1u);
    return (short)(r >> 16);
}

// packed f32 pair -> 2 bf16 in one u32 (src0 -> [15:0], src1 -> [31:16]), RNE
__device__ __forceinline__ unsigned cvtpk(float a, float b) {
    unsigned r;
    asm("v_cvt_pk_bf16_f32 %0, %1, %2" : "=v"(r) : "v"(a), "v"(b));
    return r;
}

// v_permlane32_swap_b32: new a = {a.lanes0-31, b.lanes0-31},
//                        new b = {a.lanes32-63, b.lanes32-63}.
__device__ __forceinline__ void plswap(unsigned &a, unsigned &b) {
#if defined(__has_builtin) && __has_builtin(__builtin_amdgcn_permlane32_swap)
    auto r = __builtin_amdgcn_permlane32_swap((int)a, (int)b, false, false);
    a = (unsigned)r[0]; b = (unsigned)r[1];
#else
    const bool h = (threadIdx.x & 32) != 0;
    const unsigned ax = (unsigned)__shfl_xor((int)a, 32);
    const unsigned bx = (unsigned)__shfl_xor((int)b, 32);
    const unsigned na = h ? bx : a;
    const unsigned nb = h ? b : ax;
    a = na; b = nb;
#endif
}

// ---------------------------------------------------------------------------
// cast_w: Wq/Wk/Wv -> bf16 (blocks 0-31: Wq, 32-63: Wk, 64-95: Wv)
// ---------------------------------------------------------------------------
__global__ __launch_bounds__(256) void cast_w(
    const float* __restrict__ Wq, const float* __restrict__ Wk,
    const float* __restrict__ Wv, short* __restrict__ wq_bf,
    short* __restrict__ wk_bf, short* __restrict__ wv_bf)
{
    const int b = blockIdx.x, t = threadIdx.x;
    const float* src = (b < 32) ? Wq : (b < 64) ? Wk : Wv;
    short* dst = (b < 32) ? wq_bf : (b < 64) ? wk_bf : wv_bf;
    const int i = (b & 31) * 2048 + t * 8;
    const float4 a = *reinterpret_cast<const float4*>(src + i);
    const float4 c = *reinterpret_cast<const float4*>(src + i + 4);
    uint4v u;
    u[0] = cvtpk(a.x, a.y); u[1] = cvtpk(a.z, a.w);
    u[2] = cvtpk(c.x, c.y); u[3] = cvtpk(c.z, c.w);
    *reinterpret_cast<uint4v*>(dst + i) = u;
}

// ---------------------------------------------------------------------------
// prep_mfma: k = m@Wk^T, v = m@Wv^T via MFMA (swapped-operand frags:
// A = W rows, B = mem rows -> D col = j; lanes L/L+32 share j, split f).
// Blocks 0-7: K -> FRAGMENT-ORDER blob kfb[(jt*16+s)*64+lane] (8 bf16),
//   packed with the same cvtpk+plswap transform attn uses for qA (m = j),
//   plus SoA stats. Blocks 8-15: V -> fragment-order blob
//   vfb[((jt*2+h)*8+ct)*64+lane], scalar scatter.
// MFMA 32x32x16: A[m=lane&31][k=8*hi+e], B[k=8*hi+e][n=lane&31],
//                D col=lane&31, row=(i&3)+8*(i>>2)+4*hi (+32*nt).
// ---------------------------------------------------------------------------
__global__ __launch_bounds__(256) void prep_mfma(
    const float* __restrict__ mem, const short* __restrict__ wk_bf,
    const short* __restrict__ wv_bf, short* __restrict__ kfb,
    short* __restrict__ vfb, float* __restrict__ sblob)
{
    const int t = threadIdx.x, wave = t >> 6, lane = t & 63;
    const int lo = lane & 31, hi = lane >> 5;
    const bool isV = blockIdx.x >= 8;
    const int jb = (blockIdx.x & 7) * 128 + wave * 32;  // wave's 32-j tile base
    const int j  = jb + lo;                              // this lane's j (D col)
    const int jt = jb >> 5;

    // B-frags from mem rows (fp32 -> bf16 in-register)
    bf16x8 mB[16];
    {
        const float* mr = mem + (size_t)j * HWF;
        #pragma unroll
        for (int s = 0; s < 16; ++s) {
            const float4 a = *reinterpret_cast<const float4*>(mr + 16 * s + 8 * hi);
            const float4 b = *reinterpret_cast<const float4*>(mr + 16 * s + 8 * hi + 4);
            uint4v u;
            u[0] = cvtpk(a.x, a.y); u[1] = cvtpk(a.z, a.w);
            u[2] = cvtpk(b.x, b.y); u[3] = cvtpk(b.z, b.w);
            mB[s] = __builtin_bit_cast(bf16x8, u);
        }
    }

    const short* W = isV ? wv_bf : wk_bf;
    f32x16 D[8];
    #pragma unroll
    for (int nt = 0; nt < 8; ++nt) D[nt] = (f32x16)(0.f);
    #pragma unroll
    for (int nt = 0; nt < 8; ++nt) {
        #pragma unroll
        for (int s = 0; s < 16; ++s) {
            const bf16x8 wa = *reinterpret_cast<const bf16x8*>(
                W + (size_t)(32 * nt + lo) * HWF + 16 * s + 8 * hi);
            D[nt] = MFMA32(wa, mB[s], D[nt]);
        }
    }

    if (!isV) {
        // per-j stats (in-lane over 128 regs + partner half; L/L+32 same j)
        float s = 0.f, ss = 0.f;
        #pragma unroll
        for (int nt = 0; nt < 8; ++nt)
            #pragma unroll
            for (int i = 0; i < 16; ++i) {
                const float v = D[nt][i];
                s += v; ss = __builtin_fmaf(v, v, ss);
            }
        s += __shfl_xor(s, 32);
        ss += __shfl_xor(ss, 32);
        const float km = s * (1.f / HWF);
        const float kv = (ss - s * s * (1.f / HWF)) * (1.f / (HWF - 1));

        // centered K -> fragment-order blob via cvtpk+plswap (attn qA pack, m=j)
        #pragma unroll
        for (int nt = 0; nt < 8; ++nt) {
            unsigned w[8];
            #pragma unroll
            for (int p = 0; p < 8; ++p)
                w[p] = cvtpk(D[nt][2 * p] - km, D[nt][2 * p + 1] - km);
            #pragma unroll
            for (int h = 0; h < 2; ++h) {
                unsigned a0 = w[4 * h + 0], b0 = w[4 * h + 2];
                unsigned a1 = w[4 * h + 1], b1 = w[4 * h + 3];
                plswap(a0, b0); plswap(a1, b1);
                uint4v u; u[0] = a0; u[1] = a1; u[2] = b0; u[3] = b1;
                *reinterpret_cast<uint4v*>(
                    kfb + (size_t)((jt * 16 + 2 * nt + h) * 64 + lane) * 8) = u;
            }
        }
        if (hi == 0) {
            sblob[j]        = 2.f * km;
            sblob[1024 + j] = km * km + C1v;
            sblob[2048 + j] = kv + C2v;
        }
    } else {
        // V -> fragment-order blob: element V[c=f][j] lands at
        // vfb[((jt*2+h)*8 + (f>>5))*64 + hia*32 + (f&31)][e],
        // h=(lo>>4)&1, hia=(lo>>3)&1, e=lo&7   (j = 32jt + lo)
        const int h = (lo >> 4) & 1, hia = (lo >> 3) & 1, e = lo & 7;
        #pragma unroll
        for (int nt = 0; nt < 8; ++nt) {
            #pragma unroll
            for (int i = 0; i < 16; ++i) {
                const int f = 32 * nt + (i & 3) + 8 * (i >> 2) + 4 * hi;
                vfb[(size_t)(((jt * 2 + h) * 8 + (f >> 5)) * 64
                             + hia * 32 + (f & 31)) * 8 + e] = f2bf(D[nt][i]);
            }
        }
    }
}

// ---------------------------------------------------------------------------
// attn (fragment-direct dataflow): TM=128/block, 4 waves, 2 blocks/CU.
// K and V are read straight from global FRAGMENT-ORDER blobs: each operand
// load is one fully-coalesced 1KB wave-load (lane*16B contiguous), identical
// across all 8 waves of a CU -> L1/L2 broadcast reuse. No K/V LDS, no DMA,
// NO BARRIERS in the main loop (one post-prologue barrier drains stats DMA).
// Softmax/pack/PV structure identical to verified round-4/6 (bitwise-same
// math). MFMA 32x32x16 layouts (HW-verified m74/m101):
//   A[m=lane&31][k=8*hi+e], B[k=8*hi+e][n=lane&31],
//   D col=lane&31, row=(reg&3)+8*(reg>>2)+4*hi.
// ---------------------------------------------------------------------------
__global__ __launch_bounds__(THREADS, 2) void attn(
    const float* __restrict__ x, const short* __restrict__ wq_bf,
    const short* __restrict__ kfb, const short* __restrict__ vfb,
    const float* __restrict__ sblob, float* __restrict__ out)
{
    __shared__ __align__(16) char smem[SMEM_SZ];
    const int t = threadIdx.x, wave = t >> 6, lane = t & 63;
    const int lo = lane & 31, hi = lane >> 5;
    const int rg = wave;                    // 4 row-groups of 32 tokens
    const int n0 = blockIdx.x * TM;
    const int tok = n0 + 32 * rg + lo;      // this lane's token row

    // ---- one-shot stats DMA (12 KB), drained by the single barrier below ----
    #pragma unroll
    for (int r = 0; r < 3; ++r) {
        __builtin_amdgcn_global_load_lds(
            (const __attribute__((address_space(1))) unsigned int*)
                ((const char*)sblob + r * 4096 + wave * 1024 + lane * 16),
            (__attribute__((address_space(3))) unsigned int*)
                (smem + STATS + r * 4096 + wave * 1024 + lane * 16), 16, 0, 0);
    }

    // ---- x B-frags: lane = token (n index), regs = feature ----
    bf16x8 xB[16];
    {
        const float* xr = x + (size_t)tok * HWF;
        #pragma unroll
        for (int s = 0; s < 16; ++s) {
            const float4 a = *reinterpret_cast<const float4*>(xr + 16 * s + 8 * hi);
            const float4 b = *reinterpret_cast<const float4*>(xr + 16 * s + 8 * hi + 4);
            uint4v u;
            u[0] = cvtpk(a.x, a.y); u[1] = cvtpk(a.z, a.w);
            u[2] = cvtpk(b.x, b.y); u[3] = cvtpk(b.z, b.w);
            xB[s] = __builtin_bit_cast(bf16x8, u);
        }
    }

    // ---- q = Wq @ x^T (swapped): D col = token, row = out-feature ----
    f32x16 qD[8];
    #pragma unroll
    for (int nt = 0; nt < 8; ++nt) qD[nt] = (f32x16)(0.f);
    #pragma unroll
    for (int nt = 0; nt < 8; ++nt) {
        #pragma unroll
        for (int s = 0; s < 16; ++s) {
            const bf16x8 wa = *reinterpret_cast<const bf16x8*>(
                wq_bf + (size_t)(32 * nt + lo) * HWF + 16 * s + 8 * hi);
            qD[nt] = MFMA32(wa, xB[s], qD[nt]);
        }
    }

    // ---- per-token stats fully in-lane (own half + partner half) ----
    float qs = 0.f, qss = 0.f;
    #pragma unroll
    for (int nt = 0; nt < 8; ++nt)
        #pragma unroll
        for (int i = 0; i < 16; ++i) {
            const float v = qD[nt][i];
            qs += v; qss = __builtin_fmaf(v, v, qss);
        }
    qs += __shfl_xor(qs, 32);
    qss += __shfl_xor(qss, 32);
    const float qm  = qs * (1.f / HWF);
    const float qv  = (qss - qs * qs * (1.f / HWF)) * (1.f / (HWF - 1));
    const float qm2 = qm * qm;

    // ---- qA frags in-register: cvt_pk pairs + permlane32_swap ----
    bf16x8 qA[16];
    #pragma unroll
    for (int nt = 0; nt < 8; ++nt) {
        unsigned w[8];
        #pragma unroll
        for (int p = 0; p < 8; ++p) w[p] = cvtpk(qD[nt][2 * p], qD[nt][2 * p + 1]);
        #pragma unroll
        for (int h = 0; h < 2; ++h) {
            unsigned a0 = w[4 * h + 0], b0 = w[4 * h + 2];
            unsigned a1 = w[4 * h + 1], b1 = w[4 * h + 3];
            plswap(a0, b0); plswap(a1, b1);
            uint4v u; u[0] = a0; u[1] = a1; u[2] = b0; u[3] = b1;
            qA[2 * nt + h] = __builtin_bit_cast(bf16x8, u);
        }
    }

    __syncthreads();                        // drains stats DMA; only barrier

    // ---- main loop over 32 j-tiles: barrier-free, fragment-direct ----
    f32x16 O4[8];
    #pragma unroll
    for (int ct = 0; ct < 8; ++ct) O4[ct] = (f32x16)(0.f);
    float l = 0.f;
    const short* kfrag = kfb + (size_t)lane * 8;   // + (jt*16+s)*512
    const short* vfrag = vfb + (size_t)lane * 8;   // + ((jt*2+h)*8+ct)*512

    for (int jt = 0; jt < NT; ++jt) {
        // ---- S = K @ q^T : 16 coalesced 1KB wave-loads (L1/L2 broadcast) ----
        f32x16 sacc = (f32x16)(0.f);
        __builtin_amdgcn_s_setprio(1);
        #pragma unroll
        for (int s = 0; s < 16; ++s) {
            const bf16x8 kfr = *reinterpret_cast<const bf16x8*>(
                kfrag + (size_t)(jt * 16 + s) * 512);
            sacc = MFMA32(kfr, qA[s], sacc);
        }
        __builtin_amdgcn_s_setprio(0);

        // ---- ssim -> p -> packed bf16 pairs (stats via LDS row-vectors) ----
        unsigned pw[8];
        #pragma unroll
        for (int g = 0; g < 4; ++g) {
            const int soff = (32 * jt + 8 * g + 4 * hi) * 4;
            const f32x4 a4 = *reinterpret_cast<const f32x4*>(smem + STATS + soff);
            const f32x4 b4 = *reinterpret_cast<const f32x4*>(smem + STATS + 4096 + soff);
            const f32x4 c4 = *reinterpret_cast<const f32x4*>(smem + STATS + 8192 + soff);
            float pr[4];
            #pragma unroll
            for (int q = 0; q < 4; ++q) {
                const int i = 4 * g + q;
                const float cov2 = __builtin_fmaf(sacc[i], 2.f * RK, C2v);
                const float num  = __builtin_fmaf(a4[q], qm, C1v) * cov2;
                const float den  = __builtin_fmaf(qm2 + b4[q], qv + c4[q], EPSv);
                pr[q] = __expf(__fdividef(num, den));
                l += pr[q];
            }
            pw[2 * g]     = cvtpk(pr[0], pr[1]);
            pw[2 * g + 1] = cvtpk(pr[2], pr[3]);
        }

        // ---- O += P @ V : A via permlane32_swap, B coalesced from global ----
        #pragma unroll
        for (int h = 0; h < 2; ++h) {
            unsigned a0 = pw[4 * h + 0], b0 = pw[4 * h + 2];
            unsigned a1 = pw[4 * h + 1], b1 = pw[4 * h + 3];
            plswap(a0, b0); plswap(a1, b1);
            uint4v u; u[0] = a0; u[1] = a1; u[2] = b0; u[3] = b1;
            const bf16x8 pa = __builtin_bit_cast(bf16x8, u);
            __builtin_amdgcn_s_setprio(1);
            #pragma unroll
            for (int ct = 0; ct < 8; ++ct) {
                const bf16x8 vfr = *reinterpret_cast<const bf16x8*>(
                    vfrag + (size_t)((jt * 2 + h) * 8 + ct) * 512);
                O4[ct] = MFMA32(pa, vfr, O4[ct]);
            }
            __builtin_amdgcn_s_setprio(0);
        }
    }

    // ---- l: lane-sum -> per-row via tiny wave-local LDS redistribute ----
    const float lf = l + __shfl_xor(l, 32);
    if (hi == 0)
        *reinterpret_cast<float*>(smem + LRED + (wave * 32 + lo) * 4) = lf;
    // same-wave DS ops complete in order; reads below see the writes
    float rl[16];
    #pragma unroll
    for (int g = 0; g < 4; ++g) {
        const f32x4 lv = *reinterpret_cast<const f32x4*>(
            smem + LRED + wave * 128 + (8 * g + 4 * hi) * 4);
        rl[4 * g + 0] = 1.f / lv[0];
        rl[4 * g + 1] = 1.f / lv[1];
        rl[4 * g + 2] = 1.f / lv[2];
        rl[4 * g + 3] = 1.f / lv[3];
    }

    #pragma unroll
    for (int ct = 0; ct < 8; ++ct) {
        #pragma unroll
        for (int i = 0; i < 16; ++i) {
            const int row = 32 * rg + (i & 3) + 8 * (i >> 2) + 4 * hi;
            out[(size_t)(n0 + row) * HWF + 32 * ct + lo] = O4[ct][i] * rl[i];
        }
    }
}

extern "C" void kernel_launch(void* const* d_in, const int* in_sizes, int n_in,
                              void* d_out, int out_size, void* d_ws, size_t ws_size,
                              hipStream_t stream) {
    (void)in_sizes; (void)n_in; (void)out_size; (void)ws_size;
    const float* x   = (const float*)d_in[0];
    const float* mem = (const float*)d_in[1];
    const float* Wq  = (const float*)d_in[2];
    const float* Wk  = (const float*)d_in[3];
    const float* Wv  = (const float*)d_in[4];
    float* out = (float*)d_out;

    // workspace (~1.2 MB): wq_bf | kfb (frag-order) | vfb (frag-order) | sblob
    short* wq_bf = (short*)d_ws;                        // 65536
    short* kfb   = wq_bf + 65536;                       // 262144
    short* vfb   = kfb + (size_t)MEMD * HWF;            // 262144
    float* sblob = (float*)(vfb + (size_t)MEMD * HWF);  // 3072 floats

    // Wk/Wv bf16 scratch lives in the head of `out` (64 MB): written by
    // cast_w, read by prep_mfma, fully overwritten later by attn.
    short* wk_bf = (short*)out;                         // 65536 shorts
    short* wv_bf = wk_bf + 65536;                       // 65536 shorts

    cast_w<<<96, 256, 0, stream>>>(Wq, Wk, Wv, wq_bf, wk_bf, wv_bf);
    prep_mfma<<<16, 256, 0, stream>>>(mem, wk_bf, wv_bf, kfb, vfb, sblob);
    attn<<<NROWS / TM, THREADS, 0, stream>>>(x, wq_bf, kfb, vfb, sblob, out);
}

// Round 8
// 251.160 us; speedup vs baseline: 1.3059x; 1.2478x over previous
//
#include <hip/hip_runtime.h>
#include <math.h>

typedef __attribute__((ext_vector_type(8)))  short bf16x8;   // 8 bf16 = 4 VGPR
typedef __attribute__((ext_vector_type(16))) float f32x16;   // 32x32 MFMA acc
typedef __attribute__((ext_vector_type(4)))  float f32x4;
typedef __attribute__((ext_vector_type(4)))  unsigned uint4v;

#define MFMA32(a, b, c) __builtin_amdgcn_mfma_f32_32x32x16_bf16((a), (b), (c), 0, 0, 0)

namespace {
constexpr int HWF   = 256;
constexpr int MEMD  = 1024;
constexpr int NROWS = 65536;
constexpr int TM    = 128;          // token rows per block: 4 waves x 32 rows
constexpr int NT    = MEMD / 32;    // 32 j-tiles of 32
constexpr int THREADS = 256;        // 4 waves; 2 blocks/CU (reg-capped)
constexpr float C1v  = 0.01f;
constexpr float C2v  = 0.03f;
constexpr float EPSv = 1e-8f;
constexpr float RK   = 1.0f / 255.0f;

// attn LDS map (bytes): K dbuf | V dbuf | stats (one-shot SoA) | l-redistribute
constexpr int KB0 = 0;              // 16 KB K tile (32 rows x 512B, xor-swizzled)
constexpr int KB1 = 16384;
constexpr int VB0 = 32768;          // 16 KB V tile (256 rows x 64B, xor-swizzled)
constexpr int VB1 = 49152;
constexpr int STATS = 65536;        // 12 KB: sa[1024] | sb[1024] | sc[1024]
constexpr int LRED  = STATS + 12288;  // 4 waves x 32 x f32 = 512 B
constexpr int SMEM_SZ = LRED + 512;   // 78336 B -> 2 blocks/CU
}

__device__ __forceinline__ short f2bf(float f) {            // RNE float->bf16
    union { float f; unsigned u; } v; v.f = f;
    unsigned r = v.u + 0x7fffu + ((v.u >> 16) & 1u);
    return (short)(r >> 16);
}

// packed f32 pair -> 2 bf16 in one u32 (src0 -> [15:0], src1 -> [31:16]), RNE
__device__ __forceinline__ unsigned cvtpk(float a, float b) {
    unsigned r;
    asm("v_cvt_pk_bf16_f32 %0, %1, %2" : "=v"(r) : "v"(a), "v"(b));
    return r;
}

// v_permlane32_swap_b32: a.lanes[32..63] <-> b.lanes[0..31].
__device__ __forceinline__ void plswap(unsigned &a, unsigned &b) {
#if defined(__has_builtin) && __has_builtin(__builtin_amdgcn_permlane32_swap)
    auto r = __builtin_amdgcn_permlane32_swap((int)a, (int)b, false, false);
    a = (unsigned)r[0]; b = (unsigned)r[1];
#else
    const bool h = (threadIdx.x & 32) != 0;
    const unsigned ax = (unsigned)__shfl_xor((int)a, 32);
    const unsigned bx = (unsigned)__shfl_xor((int)b, 32);
    const unsigned na = h ? bx : a;
    const unsigned nb = h ? b : ax;
    a = na; b = nb;
#endif
}

// async global->LDS DMA: 16 KB tile, wave w (of 4) copies [w*4096, w*4096+4096)
__device__ __forceinline__ void dma_tile16(const short* gbase, char* smem, int ldsbase,
                                           int wave, int lane) {
    const char* g = (const char*)gbase + wave * 4096 + lane * 16;
    char* l = smem + ldsbase + wave * 4096;
    #pragma unroll
    for (int i = 0; i < 4; ++i) {
        __builtin_amdgcn_global_load_lds(
            (const __attribute__((address_space(1))) unsigned int*)(g + i * 1024),
            (__attribute__((address_space(3))) unsigned int*)(l + i * 1024), 16, 0, 0);
    }
}

// ---------------------------------------------------------------------------
// prep (fused, 96 blocks): blocks 0-31 K-tile jt=b (swizzled blob + stats),
// blocks 32-63 V-tile jt=b-32 (swizzled blob), blocks 64-95 Wq->bf16 cast.
// K/V: k = m@Wk^T, v = m@Wv^T via MFMA, W read as f32 + in-register cvtpk
// (no separate Wk/Wv cast pass). The 4 waves split the output-feature dim:
// wave w computes nt = {2w, 2w+1} (64 of 256 f) -> 32 MFMA/wave, 4x shorter
// latency chains than the 16-block version. Stats cross-wave via tiny LDS.
// Blob byte layouts identical to the round-4-verified prep.
// MFMA 32x32x16: A[m=lane&31][k=8*hi+e], B[k=8*hi+e][n=lane&31],
//                D col=lane&31, row=(i&3)+8*(i>>2)+4*hi (+32*nt).
// ---------------------------------------------------------------------------
__global__ __launch_bounds__(256) void prep(
    const float* __restrict__ mem, const float* __restrict__ Wq,
    const float* __restrict__ Wk, const float* __restrict__ Wv,
    short* __restrict__ wq_bf, short* __restrict__ kblob,
    short* __restrict__ vblob, float* __restrict__ sblob)
{
    const int b = blockIdx.x, t = threadIdx.x;
    if (b >= 64) {                          // ---- Wq cast: 32 blocks ----
        const int i = (b - 64) * 2048 + t * 8;
        const float4 a = *reinterpret_cast<const float4*>(Wq + i);
        const float4 c = *reinterpret_cast<const float4*>(Wq + i + 4);
        uint4v u;
        u[0] = cvtpk(a.x, a.y); u[1] = cvtpk(a.z, a.w);
        u[2] = cvtpk(c.x, c.y); u[3] = cvtpk(c.z, c.w);
        *reinterpret_cast<uint4v*>(wq_bf + i) = u;
        return;
    }

    __shared__ float2 redS[4][32];
    const bool isV = b >= 32;
    const int jt = b & 31;
    const int w = t >> 6, lane = t & 63;
    const int lo = lane & 31, hi = lane >> 5;
    const int j = 32 * jt + lo;             // this lane's j (D col); ro = lo

    // B-frags from mem row j (fp32 -> bf16 in-register); shared across waves
    bf16x8 mB[16];
    {
        const float* mr = mem + (size_t)j * HWF;
        #pragma unroll
        for (int s = 0; s < 16; ++s) {
            const float4 a = *reinterpret_cast<const float4*>(mr + 16 * s + 8 * hi);
            const float4 c = *reinterpret_cast<const float4*>(mr + 16 * s + 8 * hi + 4);
            uint4v u;
            u[0] = cvtpk(a.x, a.y); u[1] = cvtpk(a.z, a.w);
            u[2] = cvtpk(c.x, c.y); u[3] = cvtpk(c.z, c.w);
            mB[s] = __builtin_bit_cast(bf16x8, u);
        }
    }

    // wave w owns nt = {2w, 2w+1}: A-frags from W rows 32*nt+lo (f32->bf16)
    const float* Wsrc = isV ? Wv : Wk;
    f32x16 D[2];
    D[0] = (f32x16)(0.f); D[1] = (f32x16)(0.f);
    #pragma unroll
    for (int n2 = 0; n2 < 2; ++n2) {
        const int nt = 2 * w + n2;
        const float* wr = Wsrc + (size_t)(32 * nt + lo) * HWF;
        #pragma unroll
        for (int s = 0; s < 16; ++s) {
            const float4 a = *reinterpret_cast<const float4*>(wr + 16 * s + 8 * hi);
            const float4 c = *reinterpret_cast<const float4*>(wr + 16 * s + 8 * hi + 4);
            uint4v u;
            u[0] = cvtpk(a.x, a.y); u[1] = cvtpk(a.z, a.w);
            u[2] = cvtpk(c.x, c.y); u[3] = cvtpk(c.z, c.w);
            const bf16x8 wa = __builtin_bit_cast(bf16x8, u);
            D[n2] = MFMA32(wa, mB[s], D[n2]);
        }
    }

    if (!isV) {
        // wave-partial stats over this wave's 64 f (own half + partner half)
        float s = 0.f, ss = 0.f;
        #pragma unroll
        for (int n2 = 0; n2 < 2; ++n2)
            #pragma unroll
            for (int i = 0; i < 16; ++i) {
                const float v = D[n2][i];
                s += v; ss = __builtin_fmaf(v, v, ss);
            }
        s += __shfl_xor(s, 32);
        ss += __shfl_xor(ss, 32);
        if (hi == 0) redS[w][lo] = make_float2(s, ss);
        __syncthreads();
        float st = 0.f, sst = 0.f;
        #pragma unroll
        for (int ww = 0; ww < 4; ++ww) {
            const float2 p = redS[ww][lo];
            st += p.x; sst += p.y;
        }
        const float km = st * (1.f / HWF);
        const float kv = (sst - st * st * (1.f / HWF)) * (1.f / (HWF - 1));

        // centered K -> swizzled blob (round-4 layout):
        // kblob[jt*8192 + ro*256 + ((4nt+a)^(ro&7))*8 + 4hi], ro = lo
        #pragma unroll
        for (int n2 = 0; n2 < 2; ++n2) {
            const int nt = 2 * w + n2;
            #pragma unroll
            for (int a = 0; a < 4; ++a) {
                short4 q4;
                q4.x = f2bf(D[n2][4 * a + 0] - km);
                q4.y = f2bf(D[n2][4 * a + 1] - km);
                q4.z = f2bf(D[n2][4 * a + 2] - km);
                q4.w = f2bf(D[n2][4 * a + 3] - km);
                *reinterpret_cast<short4*>(
                    kblob + jt * 8192 + lo * 256 +
                    (((4 * nt + a) ^ (lo & 7)) * 8) + 4 * hi) = q4;
            }
        }
        if (w == 0 && hi == 0) {
            sblob[j]        = 2.f * km;
            sblob[1024 + j] = km * km + C1v;
            sblob[2048 + j] = kv + C2v;
        }
    } else {
        // V -> swizzled blob (round-4 layout):
        // vblob[jt*8192 + f*32 + ((ro>>3)^((f>>1)&3))*8 + (ro&7)], ro = lo
        #pragma unroll
        for (int n2 = 0; n2 < 2; ++n2) {
            const int nt = 2 * w + n2;
            #pragma unroll
            for (int i = 0; i < 16; ++i) {
                const int f = 32 * nt + (i & 3) + 8 * (i >> 2) + 4 * hi;
                vblob[jt * 8192 + f * 32 +
                      (((lo >> 3) ^ ((f >> 1) & 3)) * 8) + (lo & 7)] = f2bf(D[n2][i]);
            }
        }
    }
}

// ---------------------------------------------------------------------------
// attn: byte-identical to the round-4-verified kernel (best measured: 162us).
// TM=128/block, 4 waves, 2 blocks/CU. Swapped-operand MFMA chain keeps P in
// registers; K/V LDS-staged via DMA double-buffer; V swizzle keyed (c>>1)&3.
// MFMA 32x32x16 layouts (HW-verified m74/m101):
//   A[m=lane&31][k=8*(lane>>5)+e], B[k=8*(lane>>5)+e][n=lane&31],
//   D col=lane&31, row=(reg&3)+8*(reg>>2)+4*(lane>>5).
// ---------------------------------------------------------------------------
__global__ __launch_bounds__(THREADS, 2) void attn(
    const float* __restrict__ x, const short* __restrict__ wq_bf,
    const short* __restrict__ kblob, const short* __restrict__ vblob,
    const float* __restrict__ sblob, float* __restrict__ out)
{
    __shared__ __align__(16) char smem[SMEM_SZ];
    const int t = threadIdx.x, wave = t >> 6, lane = t & 63;
    const int lo = lane & 31, hi = lane >> 5;
    const int rg = wave;                    // 4 row-groups of 32 tokens
    const int n0 = blockIdx.x * TM;
    const int tok = n0 + 32 * rg + lo;      // this lane's token row

    // ---- DMA tile 0 + one-shot stats immediately (overlaps whole prologue) ----
    dma_tile16(kblob, smem, KB0, wave, lane);
    dma_tile16(vblob, smem, VB0, wave, lane);
    #pragma unroll
    for (int r = 0; r < 3; ++r) {           // 12 KB stats: 3 rounds x 4 waves x 1 KB
        __builtin_amdgcn_global_load_lds(
            (const __attribute__((address_space(1))) unsigned int*)
                ((const char*)sblob + r * 4096 + wave * 1024 + lane * 16),
            (__attribute__((address_space(3))) unsigned int*)
                (smem + STATS + r * 4096 + wave * 1024 + lane * 16), 16, 0, 0);
    }

    // ---- x B-frags: lane = token (n index), regs = feature ----
    bf16x8 xB[16];
    {
        const float* xr = x + (size_t)tok * HWF;
        #pragma unroll
        for (int s = 0; s < 16; ++s) {
            const float4 a = *reinterpret_cast<const float4*>(xr + 16 * s + 8 * hi);
            const float4 b = *reinterpret_cast<const float4*>(xr + 16 * s + 8 * hi + 4);
            uint4v u;
            u[0] = cvtpk(a.x, a.y); u[1] = cvtpk(a.z, a.w);
            u[2] = cvtpk(b.x, b.y); u[3] = cvtpk(b.z, b.w);
            xB[s] = __builtin_bit_cast(bf16x8, u);
        }
    }

    // ---- q = Wq @ x^T (swapped): D col = token, row = out-feature ----
    f32x16 qD[8];
    #pragma unroll
    for (int nt = 0; nt < 8; ++nt) qD[nt] = (f32x16)(0.f);
    #pragma unroll
    for (int nt = 0; nt < 8; ++nt) {
        #pragma unroll
        for (int s = 0; s < 16; ++s) {
            const bf16x8 wa = *reinterpret_cast<const bf16x8*>(
                wq_bf + (size_t)(32 * nt + lo) * HWF + 16 * s + 8 * hi);
            qD[nt] = MFMA32(wa, xB[s], qD[nt]);
        }
    }

    // ---- per-token stats fully in-lane (own half + partner half) ----
    float qs = 0.f, qss = 0.f;
    #pragma unroll
    for (int nt = 0; nt < 8; ++nt)
        #pragma unroll
        for (int i = 0; i < 16; ++i) {
            const float v = qD[nt][i];
            qs += v; qss = __builtin_fmaf(v, v, qss);
        }
    qs += __shfl_xor(qs, 32);
    qss += __shfl_xor(qss, 32);
    const float qm  = qs * (1.f / HWF);
    const float qv  = (qss - qs * qs * (1.f / HWF)) * (1.f / (HWF - 1));
    const float qm2 = qm * qm;

    // ---- qA frags in-register: cvt_pk pairs + permlane32_swap ----
    bf16x8 qA[16];
    #pragma unroll
    for (int nt = 0; nt < 8; ++nt) {
        unsigned w[8];
        #pragma unroll
        for (int p = 0; p < 8; ++p) w[p] = cvtpk(qD[nt][2 * p], qD[nt][2 * p + 1]);
        #pragma unroll
        for (int h = 0; h < 2; ++h) {
            unsigned a0 = w[4 * h + 0], b0 = w[4 * h + 2];
            unsigned a1 = w[4 * h + 1], b1 = w[4 * h + 3];
            plswap(a0, b0); plswap(a1, b1);
            uint4v u; u[0] = a0; u[1] = a1; u[2] = b0; u[3] = b1;
            qA[2 * nt + h] = __builtin_bit_cast(bf16x8, u);
        }
    }

    // ---- main loop over 32 j-tiles ----
    f32x16 O4[8];
    #pragma unroll
    for (int ct = 0; ct < 8; ++ct) O4[ct] = (f32x16)(0.f);
    float l = 0.f;
    const int rx = (lo & 7);                // K xor-swizzle key
    const int vx = (lo >> 1) & 3;           // V xor-swizzle key (full bank coverage)

    for (int jt = 0; jt < NT; ++jt) {
        const int cur = jt & 1;
        const int kb = cur ? KB1 : KB0, vb = cur ? VB1 : VB0;
        const int kbn = cur ? KB0 : KB1, vbn = cur ? VB0 : VB1;
        __syncthreads();                    // drains DMA(jt); prev tile reads done
        if (jt + 1 < NT) {                  // prefetch stays in flight across compute
            dma_tile16(kblob + (size_t)(jt + 1) * 8192, smem, kbn, wave, lane);
            dma_tile16(vblob + (size_t)(jt + 1) * 8192, smem, vbn, wave, lane);
        }

        // ---- S = K @ q^T : lane = token, regs = j-offset (32 j) ----
        f32x16 sacc = (f32x16)(0.f);
        __builtin_amdgcn_s_setprio(1);
        #pragma unroll
        for (int s = 0; s < 16; ++s) {
            const bf16x8 kfr = *reinterpret_cast<const bf16x8*>(
                smem + kb + lo * 512 + (((2 * s + hi) ^ rx) * 16));
            sacc = MFMA32(kfr, qA[s], sacc);
        }
        __builtin_amdgcn_s_setprio(0);

        // ---- ssim -> p -> packed bf16 pairs (stats via row-vector reads) ----
        unsigned pw[8];
        #pragma unroll
        for (int g = 0; g < 4; ++g) {
            const int soff = (32 * jt + 8 * g + 4 * hi) * 4;
            const f32x4 a4 = *reinterpret_cast<const f32x4*>(smem + STATS + soff);
            const f32x4 b4 = *reinterpret_cast<const f32x4*>(smem + STATS + 4096 + soff);
            const f32x4 c4 = *reinterpret_cast<const f32x4*>(smem + STATS + 8192 + soff);
            float pr[4];
            #pragma unroll
            for (int q = 0; q < 4; ++q) {
                const int i = 4 * g + q;
                const float cov2 = __builtin_fmaf(sacc[i], 2.f * RK, C2v);
                const float num  = __builtin_fmaf(a4[q], qm, C1v) * cov2;
                const float den  = __builtin_fmaf(qm2 + b4[q], qv + c4[q], EPSv);
                pr[q] = __expf(__fdividef(num, den));
                l += pr[q];
            }
            pw[2 * g]     = cvtpk(pr[0], pr[1]);
            pw[2 * g + 1] = cvtpk(pr[2], pr[3]);
        }

        // ---- O += P @ V : A-frags via permlane32_swap, B from LDS ----
        #pragma unroll
        for (int h = 0; h < 2; ++h) {
            unsigned a0 = pw[4 * h + 0], b0 = pw[4 * h + 2];
            unsigned a1 = pw[4 * h + 1], b1 = pw[4 * h + 3];
            plswap(a0, b0); plswap(a1, b1);
            uint4v u; u[0] = a0; u[1] = a1; u[2] = b0; u[3] = b1;
            const bf16x8 pa = __builtin_bit_cast(bf16x8, u);
            __builtin_amdgcn_s_setprio(1);
            #pragma unroll
            for (int ct = 0; ct < 8; ++ct) {
                const bf16x8 vfr = *reinterpret_cast<const bf16x8*>(
                    smem + vb + (32 * ct + lo) * 64 + (((2 * h + hi) ^ vx) * 16));
                O4[ct] = MFMA32(pa, vfr, O4[ct]);
            }
            __builtin_amdgcn_s_setprio(0);
        }
    }

    // ---- l: lane-sum -> per-row via tiny wave-local LDS redistribute ----
    const float lf = l + __shfl_xor(l, 32);
    if (hi == 0)
        *reinterpret_cast<float*>(smem + LRED + (wave * 32 + lo) * 4) = lf;
    // same-wave DS ops complete in order; reads below see the writes
    float rl[16];
    #pragma unroll
    for (int g = 0; g < 4; ++g) {
        const f32x4 lv = *reinterpret_cast<const f32x4*>(
            smem + LRED + wave * 128 + (8 * g + 4 * hi) * 4);
        rl[4 * g + 0] = 1.f / lv[0];
        rl[4 * g + 1] = 1.f / lv[1];
        rl[4 * g + 2] = 1.f / lv[2];
        rl[4 * g + 3] = 1.f / lv[3];
    }

    #pragma unroll
    for (int ct = 0; ct < 8; ++ct) {
        #pragma unroll
        for (int i = 0; i < 16; ++i) {
            const int row = 32 * rg + (i & 3) + 8 * (i >> 2) + 4 * hi;
            out[(size_t)(n0 + row) * HWF + 32 * ct + lo] = O4[ct][i] * rl[i];
        }
    }
}

extern "C" void kernel_launch(void* const* d_in, const int* in_sizes, int n_in,
                              void* d_out, int out_size, void* d_ws, size_t ws_size,
                              hipStream_t stream) {
    (void)in_sizes; (void)n_in; (void)out_size; (void)ws_size;
    const float* x   = (const float*)d_in[0];
    const float* mem = (const float*)d_in[1];
    const float* Wq  = (const float*)d_in[2];
    const float* Wk  = (const float*)d_in[3];
    const float* Wv  = (const float*)d_in[4];
    float* out = (float*)d_out;

    // workspace (~1.2 MB): wq_bf | kblob (swizzled) | vblob (swizzled) | sblob
    short* wq_bf = (short*)d_ws;                        // 65536
    short* kblob = wq_bf + 65536;                       // 262144 (32 tiles x 8192)
    short* vblob = kblob + (size_t)MEMD * HWF;          // 262144
    float* sblob = (float*)(vblob + (size_t)MEMD * HWF);  // 3072 floats

    prep<<<96, 256, 0, stream>>>(mem, Wq, Wk, Wv, wq_bf, kblob, vblob, sblob);
    attn<<<NROWS / TM, THREADS, 0, stream>>>(x, wq_bf, kblob, vblob, sblob, out);
}